// Round 5
// baseline (172.160 us; speedup 1.0000x reference)
//
#include <hip/hip_runtime.h>
#include <cstdint>
#include <cstddef>

#define BATCH 64
#define NIN   1024
#define CIN   256
#define NC    32
#define NJC   16     // j-blocks per batch (64 j each)
#define JCH   64
#define T_EPS 1e-7f
#define CT_S  72     // cT row stride in u16 (144 B, 16B-aligned)
#define XT_SS 68     // k_convert LDS transpose row stride in u16 (136 B, 8B-aligned)

typedef __attribute__((ext_vector_type(8))) short short8;   // 8 bf16 = 4 VGPR
typedef __attribute__((ext_vector_type(4))) float floatx4;  // MFMA 16x16 acc

__device__ __forceinline__ unsigned short bf16rne(float f) {
  unsigned int u = __float_as_uint(f);
  u += 0x7FFFu + ((u >> 16) & 1u);
  return (unsigned short)(u >> 16);
}
__device__ __forceinline__ float bf2f(unsigned short h) {
  return __uint_as_float(((unsigned int)h) << 16);
}

// ---- K1: x fp32 -> bf16 in BOTH layouts (+ colsum partials for iter 0) ----
// grid (jc=16, b=64). xb row-major [b*1024+j][c]; xbT [b][jc][c:256][j:64].
__global__ __launch_bounds__(256) void k_convert(const float* __restrict__ x,
                                                 unsigned short* __restrict__ xb,
                                                 unsigned short* __restrict__ xbT,
                                                 float* __restrict__ y0p) {
  const int jc = blockIdx.x, b = blockIdx.y, t = threadIdx.x;
  __shared__ unsigned short xsT[CIN * XT_SS];   // 34 KB
  const size_t base = ((size_t)(b * NIN + jc * JCH)) * CIN;
  float acc = 0.f;
  #pragma unroll 8
  for (int j = 0; j < JCH; ++j) {
    float v = x[base + (size_t)j * CIN + t];
    acc += v;
    unsigned short h = bf16rne(v);
    xb[base + (size_t)j * CIN + t] = h;
    xsT[t * XT_SS + j] = h;
  }
  y0p[(b * NJC + jc) * CIN + t] = acc;
  __syncthreads();
  ushort4* dstv = (ushort4*)(xbT + (size_t)(b * NJC + jc) * (CIN * JCH));
  #pragma unroll
  for (int it = 0; it < 16; ++it) {
    int f = it * 256 + t;               // 0..4095 ushort4 units
    int c = f >> 4, j4 = f & 15;
    dstv[f] = *(const ushort4*)&xsT[c * XT_SS + j4 * 4];
  }
}

// ---- K2: y-reduce -> s = y@W_i -> squash -> wt(bf16) or out --------------
// grid (i=NC, b=BATCH). MODE 0: yin = y0p fp32 (NJC partials, scale 1/32).
// MODE 1: yin = ypart bf16 [b][jc][i][c], write wt. MODE 2: write out.
template <int MODE>
__global__ __launch_bounds__(256) void k_post(const void* __restrict__ yin,
                                              const float* __restrict__ W,
                                              unsigned short* __restrict__ wtout,
                                              float* __restrict__ outg) {
  const int i = blockIdx.x, b = blockIdx.y, t = threadIdx.x;
  __shared__ float Wl[CIN][36];
  __shared__ float ys[CIN];
  __shared__ float sred[8][32];
  __shared__ float os[NC];
  const float4* W4 = (const float4*)W;
  #pragma unroll
  for (int q = 0; q < 8; ++q) {
    int f = q * 256 + t;            // 0..2047
    int c = f >> 3, k4 = f & 7;
    float4 v = W4[c * (NC * 8) + i * 8 + k4];
    *(float4*)&Wl[c][k4 * 4] = v;
  }
  float a = 0.f;
  if (MODE == 0) {
    const float* y0p = (const float*)yin;
    #pragma unroll
    for (int p = 0; p < NJC; ++p) a += y0p[(b * NJC + p) * CIN + t];
    a *= (1.f / 32.f);
  } else {
    const unsigned short* yp = (const unsigned short*)yin;
    #pragma unroll
    for (int p = 0; p < NJC; ++p)
      a += bf2f(yp[(((size_t)(b * NJC + p)) * NC + i) * CIN + t]);
  }
  ys[t] = a;
  __syncthreads();
  {
    const int k = t & 31, g = t >> 5;
    float ps = 0.f;
    #pragma unroll
    for (int cc = 0; cc < 32; ++cc) {
      int c = g * 32 + cc;
      ps += ys[c] * Wl[c][k];
    }
    sred[g][k] = ps;
  }
  __syncthreads();
  const int k = t & 31;
  float s = 0.f;
  #pragma unroll
  for (int g = 0; g < 8; ++g) s += sred[g][k];
  float s2 = s * s;
  #pragma unroll
  for (int m = 1; m < 32; m <<= 1) s2 += __shfl_xor(s2, m);
  float o = s * rsqrtf(s2 + T_EPS);
  if (MODE == 2) {
    if (t < 32) outg[((size_t)b * NC + i) * 32 + t] = o;
  } else {
    if (t < 32) os[t] = o;
    __syncthreads();
    const int rot = ((t >> 3) & 7) * 4;
    float acc = 0.f;
    #pragma unroll
    for (int kkk = 0; kkk < 32; ++kkk) {
      int kk = (kkk + rot) & 31;
      acc += Wl[t][kk] * os[kk];
    }
    wtout[((size_t)b * NC + i) * CIN + t] = bf16rne(acc);
  }
}

// ---- K3: MFMA-fused  L = wt@x^T -> softmax(i) -> y = c@x -----------------
// block (jc, b), 4 waves. Phase A: wave w owns j-tile w*16+l16; A=wt (global),
// B=xb rows (global). Phase B: A=cT (LDS), B=xbT (global), wave w owns c-range
// w*64..+63. mfma_f32_16x16x32_bf16: A[m=l16][k=q*8+e], B[k=q*8+e][n=l16],
// C/D[m=q*4+reg][n=l16] (m89/m91-verified).
__global__ __launch_bounds__(256, 4) void k_fused(const unsigned short* __restrict__ xb,
                                                  const unsigned short* __restrict__ xbT,
                                                  const unsigned short* __restrict__ wt,
                                                  unsigned short* __restrict__ ypart) {
  const int jc = blockIdx.x, b = blockIdx.y, t = threadIdx.x;
  const int w = t >> 6, l16 = t & 15, q = (t >> 4) & 3;
  __shared__ unsigned short cT[NC * CT_S];   // 4.6 KB only
  const int jloc = w * 16 + l16;
  const unsigned short* xrow =
      xb + ((size_t)(b * NIN) + (size_t)jc * JCH + jloc) * CIN;
  const unsigned short* wrow = wt + (size_t)b * NC * CIN;
  floatx4 accA0 = {0.f, 0.f, 0.f, 0.f}, accA1 = {0.f, 0.f, 0.f, 0.f};
  // phase A: logits over c=256 (8 K-steps of 32)
  #pragma unroll
  for (int ks = 0; ks < 8; ++ks) {
    short8 bx = *(const short8*)(xrow + ks * 32 + q * 8);
    short8 a0 = *(const short8*)(wrow + (size_t)l16 * CIN + ks * 32 + q * 8);
    short8 a1 = *(const short8*)(wrow + (size_t)(16 + l16) * CIN + ks * 32 + q * 8);
    accA0 = __builtin_amdgcn_mfma_f32_16x16x32_bf16(a0, bx, accA0, 0, 0, 0);
    accA1 = __builtin_amdgcn_mfma_f32_16x16x32_bf16(a1, bx, accA1, 0, 0, 0);
  }
  // softmax over i=32 for column j=jloc (rows spread over quads + regs)
  {
    float m = accA0[0];
    #pragma unroll
    for (int r = 1; r < 4; ++r) m = fmaxf(m, accA0[r]);
    #pragma unroll
    for (int r = 0; r < 4; ++r) m = fmaxf(m, accA1[r]);
    m = fmaxf(m, __shfl_xor(m, 16));
    m = fmaxf(m, __shfl_xor(m, 32));
    float e0[4], e1[4], s = 0.f;
    #pragma unroll
    for (int r = 0; r < 4; ++r) {
      e0[r] = __expf(accA0[r] - m);
      e1[r] = __expf(accA1[r] - m);
      s += e0[r] + e1[r];
    }
    s += __shfl_xor(s, 16);
    s += __shfl_xor(s, 32);
    float rs = 1.f / s;
    #pragma unroll
    for (int r = 0; r < 4; ++r) {
      cT[(q * 4 + r) * CT_S + jloc]      = bf16rne(e0[r] * rs);
      cT[(16 + q * 4 + r) * CT_S + jloc] = bf16rne(e1[r] * rs);
    }
  }
  __syncthreads();   // cT complete across all 4 waves
  // phase B: y[i, cw..cw+63] = sum_j c[i,j] x[j,c]  (K=64, 2 K-steps)
  const int cw = w * 64;
  const unsigned short* xTb = xbT + (size_t)(b * NJC + jc) * (CIN * JCH);
  floatx4 accB[2][4];
  #pragma unroll
  for (int h = 0; h < 2; ++h)
    #pragma unroll
    for (int ct = 0; ct < 4; ++ct) accB[h][ct] = (floatx4){0.f, 0.f, 0.f, 0.f};
  #pragma unroll
  for (int ks = 0; ks < 2; ++ks) {
    short8 ca0 = *(const short8*)&cT[l16 * CT_S + ks * 32 + q * 8];
    short8 ca1 = *(const short8*)&cT[(16 + l16) * CT_S + ks * 32 + q * 8];
    #pragma unroll
    for (int ct = 0; ct < 4; ++ct) {
      short8 xf = *(const short8*)(xTb + (size_t)(cw + ct * 16 + l16) * JCH + ks * 32 + q * 8);
      accB[0][ct] = __builtin_amdgcn_mfma_f32_16x16x32_bf16(ca0, xf, accB[0][ct], 0, 0, 0);
      accB[1][ct] = __builtin_amdgcn_mfma_f32_16x16x32_bf16(ca1, xf, accB[1][ct], 0, 0, 0);
    }
  }
  // epilogue: bf16 partial y, layout [b][jc][i][c]
  unsigned short* yo = ypart + ((size_t)(b * NJC + jc)) * NC * CIN;
  #pragma unroll
  for (int h = 0; h < 2; ++h)
    #pragma unroll
    for (int ct = 0; ct < 4; ++ct)
      #pragma unroll
      for (int r = 0; r < 4; ++r) {
        int i = h * 16 + q * 4 + r;
        int c = cw + ct * 16 + l16;
        yo[i * CIN + c] = bf16rne(accB[h][ct][r]);
      }
}

extern "C" void kernel_launch(void* const* d_in, const int* in_sizes, int n_in,
                              void* d_out, int out_size, void* d_ws, size_t ws_size,
                              hipStream_t stream) {
  (void)in_sizes; (void)n_in; (void)out_size; (void)ws_size;
  const float* x = (const float*)d_in[0];
  const float* W = (const float*)d_in[1];
  float* out = (float*)d_out;
  char* ws = (char*)d_ws;
  // ws: xb 32MiB | xbT 32MiB | wt 1MiB | ypart 16MiB | y0p 1MiB  (82 MiB)
  unsigned short* xbuf  = (unsigned short*)ws;
  unsigned short* xbufT = (unsigned short*)(ws + (32ull << 20));
  unsigned short* wtb   = (unsigned short*)(ws + (64ull << 20));
  unsigned short* ypart = (unsigned short*)(ws + (65ull << 20));
  float*          y0p   = (float*)(ws + (81ull << 20));

  dim3 gfuse(NJC, BATCH);     // (16, 64)
  dim3 gpost(NC, BATCH);      // (32, 64)
  k_convert<<<gfuse, 256, 0, stream>>>(x, xbuf, xbufT, y0p);
  k_post<0><<<gpost, 256, 0, stream>>>(y0p, W, wtb, nullptr);        // iter 0
  k_fused<<<gfuse, 256, 0, stream>>>(xbuf, xbufT, wtb, ypart);       // iter 1
  k_post<1><<<gpost, 256, 0, stream>>>(ypart, W, wtb, nullptr);
  k_fused<<<gfuse, 256, 0, stream>>>(xbuf, xbufT, wtb, ypart);       // iter 2
  k_post<2><<<gpost, 256, 0, stream>>>(ypart, W, nullptr, out);
}

// Round 6
// 159.238 us; speedup vs baseline: 1.0811x; 1.0811x over previous
//
#include <hip/hip_runtime.h>
#include <cstdint>
#include <cstddef>

#define BATCH 64
#define NIN   1024
#define CIN   256
#define NC    32
#define NJC   16     // j-blocks per batch (64 j each)
#define JCH   64
#define T_EPS 1e-7f
#define CT_S  72     // cT row stride in u16 (144 B; 72%8==0 so b128-aligned)

typedef __attribute__((ext_vector_type(8))) short short8;   // 8 bf16 = 4 VGPR
typedef __attribute__((ext_vector_type(4))) float floatx4;  // MFMA 16x16 acc

__device__ __forceinline__ unsigned short bf16rne(float f) {
  unsigned int u = __float_as_uint(f);
  u += 0x7FFFu + ((u >> 16) & 1u);
  return (unsigned short)(u >> 16);
}
__device__ __forceinline__ float bf2f(unsigned short h) {
  return __uint_as_float(((unsigned int)h) << 16);
}

// swizzled u16 index into the 64x256 LDS x-tile: 16B chunks XOR-permuted per j
// so that phase-A (row-segment b128) AND phase-B (column u16 gather) are both
// <=2-way bank-conflicted.
__device__ __forceinline__ int xsw(int j, int c) {
  return j * 256 + ((((c >> 3) ^ (j & 7) ^ ((j >> 3) & 7)) << 3) | (c & 7));
}

// ---- K1: x fp32 -> bf16 row-major + colsum partials (iter-0 uniform c) ----
// grid (jc=16, b=64); thread (jj = t>>6 in 0..3, c4 = t&63 float4 column)
__global__ __launch_bounds__(256) void k_convert(const float* __restrict__ x,
                                                 unsigned short* __restrict__ xb,
                                                 float* __restrict__ y0p) {
  const int jc = blockIdx.x, b = blockIdx.y, t = threadIdx.x;
  const int jj = t >> 6, c4 = t & 63;
  __shared__ float4 red[4][64];
  const float4* xg = (const float4*)(x + ((size_t)(b * NIN + jc * JCH)) * CIN);
  ushort4* xo = (ushort4*)(xb + ((size_t)(b * NIN + jc * JCH)) * CIN);
  float4 acc = make_float4(0.f, 0.f, 0.f, 0.f);
  #pragma unroll
  for (int jr = 0; jr < 16; ++jr) {
    int j = jr * 4 + jj;
    float4 v = xg[j * 64 + c4];
    acc.x += v.x; acc.y += v.y; acc.z += v.z; acc.w += v.w;
    ushort4 h;
    h.x = bf16rne(v.x); h.y = bf16rne(v.y);
    h.z = bf16rne(v.z); h.w = bf16rne(v.w);
    xo[j * 64 + c4] = h;
  }
  red[jj][c4] = acc;
  __syncthreads();
  if (t < 64) {
    float4 s = red[0][t];
    #pragma unroll
    for (int p = 1; p < 4; ++p) {
      s.x += red[p][t].x; s.y += red[p][t].y;
      s.z += red[p][t].z; s.w += red[p][t].w;
    }
    *(float4*)&y0p[(b * NJC + jc) * CIN + t * 4] = s;
  }
}

// ---- K2: y-reduce -> s = y@W_i -> squash -> wt(bf16) or out --------------
// grid (i=NC, b=BATCH). MODE 0: yin = y0p fp32 (NJC partials, scale 1/32).
// MODE 1: yin = ypart bf16 [b][jc][i][c], write wt. MODE 2: write out.
template <int MODE>
__global__ __launch_bounds__(256) void k_post(const void* __restrict__ yin,
                                              const float* __restrict__ W,
                                              unsigned short* __restrict__ wtout,
                                              float* __restrict__ outg) {
  const int i = blockIdx.x, b = blockIdx.y, t = threadIdx.x;
  __shared__ float Wl[CIN][36];
  __shared__ float ys[CIN];
  __shared__ float sred[8][32];
  __shared__ float os[NC];
  const float4* W4 = (const float4*)W;
  #pragma unroll
  for (int q = 0; q < 8; ++q) {
    int f = q * 256 + t;            // 0..2047
    int c = f >> 3, k4 = f & 7;
    float4 v = W4[c * (NC * 8) + i * 8 + k4];
    *(float4*)&Wl[c][k4 * 4] = v;
  }
  float a = 0.f;
  if (MODE == 0) {
    const float* y0p = (const float*)yin;
    #pragma unroll
    for (int p = 0; p < NJC; ++p) a += y0p[(b * NJC + p) * CIN + t];
    a *= (1.f / 32.f);
  } else {
    const unsigned short* yp = (const unsigned short*)yin;
    #pragma unroll
    for (int p = 0; p < NJC; ++p)
      a += bf2f(yp[(((size_t)(b * NJC + p)) * NC + i) * CIN + t]);
  }
  ys[t] = a;
  __syncthreads();
  {
    const int k = t & 31, g = t >> 5;
    float ps = 0.f;
    #pragma unroll
    for (int cc = 0; cc < 32; ++cc) {
      int c = g * 32 + cc;
      ps += ys[c] * Wl[c][k];
    }
    sred[g][k] = ps;
  }
  __syncthreads();
  const int k = t & 31;
  float s = 0.f;
  #pragma unroll
  for (int g = 0; g < 8; ++g) s += sred[g][k];
  float s2 = s * s;
  #pragma unroll
  for (int m = 1; m < 32; m <<= 1) s2 += __shfl_xor(s2, m);
  float o = s * rsqrtf(s2 + T_EPS);
  if (MODE == 2) {
    if (t < 32) outg[((size_t)b * NC + i) * 32 + t] = o;
  } else {
    if (t < 32) os[t] = o;
    __syncthreads();
    const int rot = ((t >> 3) & 7) * 4;
    float acc = 0.f;
    #pragma unroll
    for (int kkk = 0; kkk < 32; ++kkk) {
      int kk = (kkk + rot) & 31;
      acc += Wl[t][kk] * os[kk];
    }
    wtout[((size_t)b * NC + i) * CIN + t] = bf16rne(acc);
  }
}

// ---- K3: MFMA-fused  L = wt@x^T -> softmax(i) -> y = c@x -----------------
// block (jc, b), 4 waves. x-tile staged once in swizzled LDS; phase A reads
// row-segment b128 frags, phase B reads column u16 frags from the SAME tile.
// wt A-frags straight from global (L2-hot). mfma_f32_16x16x32_bf16:
// A[m=l16][k=q*8+e], B[k=q*8+e][n=l16], C/D[m=q*4+reg][n=l16].
__global__ __launch_bounds__(256, 4) void k_fused(const unsigned short* __restrict__ xb,
                                                  const unsigned short* __restrict__ wt,
                                                  unsigned short* __restrict__ ypart) {
  const int jc = blockIdx.x, b = blockIdx.y, t = threadIdx.x;
  const int w = t >> 6, l16 = t & 15, q = (t >> 4) & 3;
  __shared__ unsigned short xs[64 * 256];    // 32 KB, swizzled
  __shared__ unsigned short cT[NC * CT_S];   // 4.6 KB
  // stage the 64x256 bf16 tile (coalesced 16B chunks, swizzled dst)
  {
    const short8* xg =
        (const short8*)(xb + ((size_t)(b * NIN) + (size_t)jc * JCH) * CIN);
    #pragma unroll
    for (int it = 0; it < 8; ++it) {
      int f = it * 256 + t;               // 0..2047 16B chunks
      int j = f >> 5, ch = f & 31;
      *(short8*)&xs[xsw(j, ch * 8)] = xg[f];
    }
  }
  const int jloc = w * 16 + l16;
  const unsigned short* wrow = wt + (size_t)b * NC * CIN;
  floatx4 accA0 = {0.f, 0.f, 0.f, 0.f}, accA1 = {0.f, 0.f, 0.f, 0.f};
  __syncthreads();
  // phase A: logits over c=256 (8 K-steps of 32)
  #pragma unroll
  for (int ks = 0; ks < 8; ++ks) {
    short8 bx = *(const short8*)&xs[xsw(jloc, ks * 32 + q * 8)];
    short8 a0 = *(const short8*)(wrow + (size_t)l16 * CIN + ks * 32 + q * 8);
    short8 a1 = *(const short8*)(wrow + (size_t)(16 + l16) * CIN + ks * 32 + q * 8);
    accA0 = __builtin_amdgcn_mfma_f32_16x16x32_bf16(a0, bx, accA0, 0, 0, 0);
    accA1 = __builtin_amdgcn_mfma_f32_16x16x32_bf16(a1, bx, accA1, 0, 0, 0);
  }
  // softmax over i=32 for column j=jloc (rows spread over quads + regs)
  {
    float m = accA0[0];
    #pragma unroll
    for (int r = 1; r < 4; ++r) m = fmaxf(m, accA0[r]);
    #pragma unroll
    for (int r = 0; r < 4; ++r) m = fmaxf(m, accA1[r]);
    m = fmaxf(m, __shfl_xor(m, 16));
    m = fmaxf(m, __shfl_xor(m, 32));
    float e0[4], e1[4], s = 0.f;
    #pragma unroll
    for (int r = 0; r < 4; ++r) {
      e0[r] = __expf(accA0[r] - m);
      e1[r] = __expf(accA1[r] - m);
      s += e0[r] + e1[r];
    }
    s += __shfl_xor(s, 16);
    s += __shfl_xor(s, 32);
    float rs = 1.f / s;
    #pragma unroll
    for (int r = 0; r < 4; ++r) {
      cT[(q * 4 + r) * CT_S + jloc]      = bf16rne(e0[r] * rs);
      cT[(16 + q * 4 + r) * CT_S + jloc] = bf16rne(e1[r] * rs);
    }
  }
  __syncthreads();   // cT complete across all 4 waves
  // phase B: y[i, cw..cw+63] = sum_j c[i,j] x[j,c]  (K=64, 2 K-steps)
  const int cw = w * 64;
  floatx4 accB[2][4];
  #pragma unroll
  for (int h = 0; h < 2; ++h)
    #pragma unroll
    for (int ct = 0; ct < 4; ++ct) accB[h][ct] = (floatx4){0.f, 0.f, 0.f, 0.f};
  #pragma unroll
  for (int ks = 0; ks < 2; ++ks) {
    short8 ca0 = *(const short8*)&cT[l16 * CT_S + ks * 32 + q * 8];
    short8 ca1 = *(const short8*)&cT[(16 + l16) * CT_S + ks * 32 + q * 8];
    #pragma unroll
    for (int ct = 0; ct < 4; ++ct) {
      const int c = cw + ct * 16 + l16;
      short8 xf;
      #pragma unroll
      for (int e = 0; e < 8; ++e)
        xf[e] = (short)xs[xsw(ks * 32 + q * 8 + e, c)];
      accB[0][ct] = __builtin_amdgcn_mfma_f32_16x16x32_bf16(ca0, xf, accB[0][ct], 0, 0, 0);
      accB[1][ct] = __builtin_amdgcn_mfma_f32_16x16x32_bf16(ca1, xf, accB[1][ct], 0, 0, 0);
    }
  }
  // epilogue: bf16 partial y, layout [b][jc][i][c]
  unsigned short* yo = ypart + ((size_t)(b * NJC + jc)) * NC * CIN;
  #pragma unroll
  for (int h = 0; h < 2; ++h)
    #pragma unroll
    for (int ct = 0; ct < 4; ++ct)
      #pragma unroll
      for (int r = 0; r < 4; ++r) {
        int i = h * 16 + q * 4 + r;
        int c = cw + ct * 16 + l16;
        yo[i * CIN + c] = bf16rne(accB[h][ct][r]);
      }
}

extern "C" void kernel_launch(void* const* d_in, const int* in_sizes, int n_in,
                              void* d_out, int out_size, void* d_ws, size_t ws_size,
                              hipStream_t stream) {
  (void)in_sizes; (void)n_in; (void)out_size; (void)ws_size;
  const float* x = (const float*)d_in[0];
  const float* W = (const float*)d_in[1];
  float* out = (float*)d_out;
  char* ws = (char*)d_ws;
  // ws: xb 32MiB | wt 1MiB | ypart 16MiB | y0p 1MiB
  unsigned short* xbuf  = (unsigned short*)ws;
  unsigned short* wtb   = (unsigned short*)(ws + (32ull << 20));
  unsigned short* ypart = (unsigned short*)(ws + (33ull << 20));
  float*          y0p   = (float*)(ws + (49ull << 20));

  dim3 gfuse(NJC, BATCH);     // (16, 64)
  dim3 gpost(NC, BATCH);      // (32, 64)
  k_convert<<<gfuse, 256, 0, stream>>>(x, xbuf, y0p);
  k_post<0><<<gpost, 256, 0, stream>>>(y0p, W, wtb, nullptr);     // iter 0
  k_fused<<<gfuse, 256, 0, stream>>>(xbuf, wtb, ypart);           // iter 1
  k_post<1><<<gpost, 256, 0, stream>>>(ypart, W, wtb, nullptr);
  k_fused<<<gfuse, 256, 0, stream>>>(xbuf, wtb, ypart);           // iter 2
  k_post<2><<<gpost, 256, 0, stream>>>(ypart, W, nullptr, out);
}

// Round 9
// 154.496 us; speedup vs baseline: 1.1143x; 1.0307x over previous
//
#include <hip/hip_runtime.h>
#include <cstdint>
#include <cstddef>

#define BATCH 64
#define NIN   1024
#define CIN   256
#define NC    32
#define NJC   16     // j-blocks per batch (64 j each)
#define JCH   64
#define T_EPS 1e-7f
#define CT_S  72     // cT row stride in u16 (144 B)

typedef __attribute__((ext_vector_type(8))) short short8;   // 8 bf16 = 4 VGPR
typedef __attribute__((ext_vector_type(4))) float floatx4;  // MFMA 16x16 acc

__device__ __forceinline__ unsigned short bf16rne(float f) {
  unsigned int u = __float_as_uint(f);
  u += 0x7FFFu + ((u >> 16) & 1u);
  return (unsigned short)(u >> 16);
}
__device__ __forceinline__ float bf2f(unsigned short h) {
  return __uint_as_float(((unsigned int)h) << 16);
}
// swizzled u16 index into the 64x256 LDS x-tile (16B chunks XOR-permuted per j)
__device__ __forceinline__ int xsw(int j, int c) {
  return j * 256 + ((((c >> 3) ^ (j & 7) ^ ((j >> 3) & 7)) << 3) | (c & 7));
}

// ---- K1: x fp32 -> bf16 row-major + colsum partials + Wi build (b==0) ----
// grid (jc=16, b=64). Wi[i][c][k] bf16 = W[c][i*32+k].
__global__ __launch_bounds__(256) void k_convert(const float* __restrict__ x,
                                                 const float* __restrict__ W,
                                                 unsigned short* __restrict__ xb,
                                                 unsigned short* __restrict__ Wi,
                                                 float* __restrict__ y0p) {
  const int jc = blockIdx.x, b = blockIdx.y, t = threadIdx.x;
  const int jj = t >> 6, c4 = t & 63;
  __shared__ float4 red[4][64];
  const float4* xg = (const float4*)(x + ((size_t)(b * NIN + jc * JCH)) * CIN);
  ushort4* xo = (ushort4*)(xb + ((size_t)(b * NIN + jc * JCH)) * CIN);
  float4 acc = make_float4(0.f, 0.f, 0.f, 0.f);
  #pragma unroll
  for (int jr = 0; jr < 16; ++jr) {
    int j = jr * 4 + jj;
    float4 v = xg[j * 64 + c4];
    acc.x += v.x; acc.y += v.y; acc.z += v.z; acc.w += v.w;
    ushort4 h;
    h.x = bf16rne(v.x); h.y = bf16rne(v.y);
    h.z = bf16rne(v.z); h.w = bf16rne(v.w);
    xo[j * 64 + c4] = h;
  }
  red[jj][c4] = acc;
  if (b == 0) {
    // build Wi rows for i = jc*2, jc*2+1 ; thread t <-> c
    #pragma unroll
    for (int i2 = 0; i2 < 2; ++i2) {
      int i = jc * 2 + i2;
      const float4* wsrc = (const float4*)(W + (size_t)t * 1024 + i * 32);
      unsigned short* wdst = Wi + ((size_t)i * CIN + t) * NC;
      #pragma unroll
      for (int k4 = 0; k4 < 8; ++k4) {
        float4 v = wsrc[k4];
        ushort4 h;
        h.x = bf16rne(v.x); h.y = bf16rne(v.y);
        h.z = bf16rne(v.z); h.w = bf16rne(v.w);
        *(ushort4*)&wdst[k4 * 4] = h;
      }
    }
  }
  __syncthreads();
  if (t < 64) {
    float4 s = red[0][t];
    #pragma unroll
    for (int p = 1; p < 4; ++p) {
      s.x += red[p][t].x; s.y += red[p][t].y;
      s.z += red[p][t].z; s.w += red[p][t].w;
    }
    *(float4*)&y0p[(b * NJC + jc) * CIN + t * 4] = s;
  }
}

// ---- K2 v2: y-reduce -> s = y@W_i -> squash -> wt(bf16) or out -----------
// grid (i=NC, b=BATCH). NO W staging: Wi[i][c][k] bf16 read直接 (L1/L2-hot).
// MODE 0: yin=y0p fp32 (scale 1/32). MODE 1: yin=ypart bf16 [b][jc][i][c],
// write wt. MODE 2: write out.
template <int MODE>
__global__ __launch_bounds__(256) void k_post(const void* __restrict__ yin,
                                              const unsigned short* __restrict__ Wi,
                                              unsigned short* __restrict__ wtout,
                                              float* __restrict__ outg) {
  const int i = blockIdx.x, b = blockIdx.y, t = threadIdx.x;
  __shared__ float ys[CIN];
  __shared__ float sred[8][32];
  __shared__ float os[NC];
  // step 1: reduce partial y for (b,i); lane t <-> c
  float a = 0.f;
  if (MODE == 0) {
    const float* y0p = (const float*)yin;
    #pragma unroll
    for (int p = 0; p < NJC; ++p) a += y0p[(b * NJC + p) * CIN + t];
    a *= (1.f / 32.f);
  } else {
    const unsigned short* yp = (const unsigned short*)yin;
    #pragma unroll
    for (int p = 0; p < NJC; ++p)
      a += bf2f(yp[(((size_t)(b * NJC + p)) * NC + i) * CIN + t]);
  }
  ys[t] = a;
  __syncthreads();
  // step 2: s[k] partials over c (8 groups x 32 k); rotated c start keeps the
  // ys broadcast reads conflict-free (banks (g*32+(cc+4g))%32 distinct per g)
  const unsigned short* Wis = Wi + (size_t)i * CIN * NC;
  {
    const int k = t & 31, g = t >> 5;
    float ps = 0.f;
    #pragma unroll
    for (int cc = 0; cc < 32; ++cc) {
      int c = g * 32 + ((cc + g * 4) & 31);
      ps += ys[c] * bf2f(Wis[c * NC + k]);
    }
    sred[g][k] = ps;
  }
  __syncthreads();
  const int k = t & 31;
  float s = 0.f;
  #pragma unroll
  for (int g = 0; g < 8; ++g) s += sred[g][k];
  float s2 = s * s;
  #pragma unroll
  for (int m = 1; m < 32; m <<= 1) s2 += __shfl_xor(s2, m);
  float o = s * rsqrtf(s2 + T_EPS);
  if (MODE == 2) {
    if (t < 32) outg[((size_t)b * NC + i) * 32 + t] = o;
  } else {
    if (t < 32) os[t] = o;
    __syncthreads();
    // step 4: wt[b,i,c=t] = sum_k os[k] * Wi[i][t][k]  (b128 coalesced)
    float acc = 0.f;
    const short8* wrow = (const short8*)(Wis + (size_t)t * NC);
    #pragma unroll
    for (int k8 = 0; k8 < 4; ++k8) {
      short8 wv = wrow[k8];
      #pragma unroll
      for (int e = 0; e < 8; ++e)
        acc += os[k8 * 8 + e] * bf2f((unsigned short)wv[e]);
    }
    wtout[((size_t)b * NC + i) * CIN + t] = bf16rne(acc);
  }
}

// ---- K3: MFMA-fused  L = wt@x^T -> softmax(i) -> y = c@x  (R6, unchanged) -
__global__ __launch_bounds__(256, 4) void k_fused(const unsigned short* __restrict__ xb,
                                                  const unsigned short* __restrict__ wt,
                                                  unsigned short* __restrict__ ypart) {
  const int jc = blockIdx.x, b = blockIdx.y, t = threadIdx.x;
  const int w = t >> 6, l16 = t & 15, q = (t >> 4) & 3;
  __shared__ unsigned short xs[64 * 256];    // 32 KB, swizzled
  __shared__ unsigned short cT[NC * CT_S];   // 4.6 KB
  {
    const short8* xg =
        (const short8*)(xb + ((size_t)(b * NIN) + (size_t)jc * JCH) * CIN);
    #pragma unroll
    for (int it = 0; it < 8; ++it) {
      int f = it * 256 + t;               // 0..2047 16B chunks
      int j = f >> 5, ch = f & 31;
      *(short8*)&xs[xsw(j, ch * 8)] = xg[f];
    }
  }
  const int jloc = w * 16 + l16;
  const unsigned short* wrow = wt + (size_t)b * NC * CIN;
  floatx4 accA0 = {0.f, 0.f, 0.f, 0.f}, accA1 = {0.f, 0.f, 0.f, 0.f};
  __syncthreads();
  #pragma unroll
  for (int ks = 0; ks < 8; ++ks) {
    short8 bx = *(const short8*)&xs[xsw(jloc, ks * 32 + q * 8)];
    short8 a0 = *(const short8*)(wrow + (size_t)l16 * CIN + ks * 32 + q * 8);
    short8 a1 = *(const short8*)(wrow + (size_t)(16 + l16) * CIN + ks * 32 + q * 8);
    accA0 = __builtin_amdgcn_mfma_f32_16x16x32_bf16(a0, bx, accA0, 0, 0, 0);
    accA1 = __builtin_amdgcn_mfma_f32_16x16x32_bf16(a1, bx, accA1, 0, 0, 0);
  }
  {
    float m = accA0[0];
    #pragma unroll
    for (int r = 1; r < 4; ++r) m = fmaxf(m, accA0[r]);
    #pragma unroll
    for (int r = 0; r < 4; ++r) m = fmaxf(m, accA1[r]);
    m = fmaxf(m, __shfl_xor(m, 16));
    m = fmaxf(m, __shfl_xor(m, 32));
    float e0[4], e1[4], s = 0.f;
    #pragma unroll
    for (int r = 0; r < 4; ++r) {
      e0[r] = __expf(accA0[r] - m);
      e1[r] = __expf(accA1[r] - m);
      s += e0[r] + e1[r];
    }
    s += __shfl_xor(s, 16);
    s += __shfl_xor(s, 32);
    float rs = 1.f / s;
    #pragma unroll
    for (int r = 0; r < 4; ++r) {
      cT[(q * 4 + r) * CT_S + jloc]      = bf16rne(e0[r] * rs);
      cT[(16 + q * 4 + r) * CT_S + jloc] = bf16rne(e1[r] * rs);
    }
  }
  __syncthreads();
  const int cw = w * 64;
  floatx4 accB[2][4];
  #pragma unroll
  for (int h = 0; h < 2; ++h)
    #pragma unroll
    for (int ct = 0; ct < 4; ++ct) accB[h][ct] = (floatx4){0.f, 0.f, 0.f, 0.f};
  #pragma unroll
  for (int ks = 0; ks < 2; ++ks) {
    short8 ca0 = *(const short8*)&cT[l16 * CT_S + ks * 32 + q * 8];
    short8 ca1 = *(const short8*)&cT[(16 + l16) * CT_S + ks * 32 + q * 8];
    #pragma unroll
    for (int ct = 0; ct < 4; ++ct) {
      const int c = cw + ct * 16 + l16;
      short8 xf;
      #pragma unroll
      for (int e = 0; e < 8; ++e)
        xf[e] = (short)xs[xsw(ks * 32 + q * 8 + e, c)];
      accB[0][ct] = __builtin_amdgcn_mfma_f32_16x16x32_bf16(ca0, xf, accB[0][ct], 0, 0, 0);
      accB[1][ct] = __builtin_amdgcn_mfma_f32_16x16x32_bf16(ca1, xf, accB[1][ct], 0, 0, 0);
    }
  }
  unsigned short* yo = ypart + ((size_t)(b * NJC + jc)) * NC * CIN;
  #pragma unroll
  for (int h = 0; h < 2; ++h)
    #pragma unroll
    for (int ct = 0; ct < 4; ++ct)
      #pragma unroll
      for (int r = 0; r < 4; ++r) {
        int i = h * 16 + q * 4 + r;
        int c = cw + ct * 16 + l16;
        yo[i * CIN + c] = bf16rne(accB[h][ct][r]);
      }
}

extern "C" void kernel_launch(void* const* d_in, const int* in_sizes, int n_in,
                              void* d_out, int out_size, void* d_ws, size_t ws_size,
                              hipStream_t stream) {
  (void)in_sizes; (void)n_in; (void)out_size; (void)ws_size;
  const float* x = (const float*)d_in[0];
  const float* W = (const float*)d_in[1];
  float* out = (float*)d_out;
  char* ws = (char*)d_ws;
  // ws: xb 32MiB | wt 1MiB | ypart 16MiB | y0p 1MiB | Wi 512KiB
  unsigned short* xbuf  = (unsigned short*)ws;
  unsigned short* wtb   = (unsigned short*)(ws + (32ull << 20));
  unsigned short* ypart = (unsigned short*)(ws + (33ull << 20));
  float*          y0p   = (float*)(ws + (49ull << 20));
  unsigned short* Wi    = (unsigned short*)(ws + (50ull << 20));

  dim3 gfuse(NJC, BATCH);     // (16, 64)
  dim3 gpost(NC, BATCH);      // (32, 64)
  k_convert<<<gfuse, 256, 0, stream>>>(x, W, xbuf, Wi, y0p);
  k_post<0><<<gpost, 256, 0, stream>>>(y0p, Wi, wtb, nullptr);    // iter 0
  k_fused<<<gfuse, 256, 0, stream>>>(xbuf, wtb, ypart);           // iter 1
  k_post<1><<<gpost, 256, 0, stream>>>(ypart, Wi, wtb, nullptr);
  k_fused<<<gfuse, 256, 0, stream>>>(xbuf, wtb, ypart);           // iter 2
  k_post<2><<<gpost, 256, 0, stream>>>(ypart, Wi, nullptr, out);
}